// Round 3
// baseline (107.510 us; speedup 1.0000x reference)
//
#include <hip/hip_runtime.h>
#include <stdint.h>

typedef unsigned short ushort_t;
typedef __attribute__((ext_vector_type(8))) short short8v;   // 8 x bf16
typedef __attribute__((ext_vector_type(4))) float f32x4;     // MFMA acc

#define NSPLIT 4

// ws: At bf16 [16][128][512] (2 MiB) | Wt bf16 [16][512][512] (8 MiB) | P f32 [4][16][128][512] (16 MiB)
#define AT_ELEMS (16u * 128u * 512u)
#define WT_ELEMS (16u * 512u * 512u)
#define P_OFF_BYTES ((size_t)(AT_ELEMS + WT_ELEMS) * 2u)
#define P_ELEMS ((size_t)NSPLIT * 16 * 128 * 512)
#define WS_NEEDED (P_OFF_BYTES + P_ELEMS * 4u)

__host__ __device__ constexpr int ga_sign_i(int a, int b) {
  int t = a >> 1, sw = 0;
  while (t) {
    int x = t & b;
    while (x) { sw += x & 1; x >>= 1; }
    t >>= 1;
  }
  return (sw & 1) ? -1 : 1;
}

struct SignTab { int s[16][16]; };
constexpr SignTab make_tab() {
  SignTab t{};
  for (int i = 0; i < 16; i++)
    for (int j = 0; j < 16; j++) t.s[i][j] = ga_sign_i(i, j);
  return t;
}
constexpr SignTab STAB = make_tab();

__device__ __forceinline__ ushort_t f2bf(float f) {
  unsigned u = __float_as_uint(f);
  u = (u + 0x7FFFu + ((u >> 16) & 1u)) >> 16;   // RNE
  return (ushort_t)u;
}

__device__ __forceinline__ short8v neg_bf16x8(short8v v) {
  const short m = (short)0x8000;
  return v ^ (short8v){m, m, m, m, m, m, m, m};
}

// ---------------------------------------------------------------------------
// prep: At[j][b][n] = bf16(x[b,n,j]);  Wt[j][u][n] = bf16(w[u,n,j])
// thread <-> (j, row, n-octet): 8 strided scalar loads -> one uint4 store.
// ---------------------------------------------------------------------------
#define PREP_XT (16 * 128 * 64)              // 131072
#define PREP_TOT (PREP_XT + 16 * 512 * 64)   // 655360 -> 2560 blocks

__global__ __launch_bounds__(256) void prep_kernel(const float* __restrict__ x,
                                                   const float* __restrict__ w,
                                                   ushort_t* __restrict__ At,
                                                   ushort_t* __restrict__ Wt) {
  int tid = blockIdx.x * 256 + threadIdx.x;
  if (tid < PREP_XT) {
    int n8 = tid & 63;
    int bj = tid >> 6;
    int b = bj & 127, j = bj >> 7;
    ushort_t o[8];
#pragma unroll
    for (int r = 0; r < 8; r++)
      o[r] = f2bf(x[((size_t)(b * 512 + n8 * 8 + r)) * 16 + j]);
    *(uint4*)(At + ((size_t)(j * 128 + b)) * 512 + n8 * 8) = *(const uint4*)o;
  } else {
    int t = tid - PREP_XT;
    int n8 = t & 63;
    int uj = t >> 6;
    int u = uj & 511, j = uj >> 9;
    ushort_t o[8];
#pragma unroll
    for (int r = 0; r < 8; r++)
      o[r] = f2bf(w[((size_t)(u * 512 + n8 * 8 + r)) * 16 + j]);
    *(uint4*)(Wt + ((size_t)(j * 512 + u)) * 512 + n8 * 8) = *(const uint4*)o;
  }
}

// ---------------------------------------------------------------------------
// gemm: block = 16b x 32u x all 16k, nsplit=4 (n-range 128 = 4 chunks of 32).
// LDS 48 KB: Xs[16j][16b][32n] | Ws[16j][32u][32n]; 64B rows, 16B chunks
// XOR-swizzled: content chunk q at position q ^ (r&3) ^ ((r>>2)&3).
// Wave W: k = 4W + kl. Per jh-group, i = 4(jh^W) + (jl^kl); sign compile-time.
// ---------------------------------------------------------------------------
template <int W>
__device__ __forceinline__ void compute_chunk(const char* sm, int lbx,
                                              f32x4 (&acc)[4][2]) {
#pragma unroll
  for (int jh = 0; jh < 4; jh++) {
    const int ig = jh ^ W;
    short8v av[4], avn[4], bv[4][2];
#pragma unroll
    for (int il = 0; il < 4; il++) {
      av[il] = *(const short8v*)(sm + (ig * 4 + il) * 1024 + lbx);
      avn[il] = neg_bf16x8(av[il]);
    }
#pragma unroll
    for (int jl = 0; jl < 4; jl++)
#pragma unroll
      for (int g = 0; g < 2; g++)
        bv[jl][g] = *(const short8v*)(sm + 16384 + (jh * 4 + jl) * 2048 + g * 1024 + lbx);
#pragma unroll
    for (int kl = 0; kl < 4; kl++) {
#pragma unroll
      for (int jl = 0; jl < 4; jl++) {
        const int il = jl ^ kl;
        const int i = ig * 4 + il;          // compile-time after unroll
        const int j = jh * 4 + jl;
        const short8v a = (STAB.s[i][j] < 0) ? avn[il] : av[il];
        acc[kl][0] = __builtin_amdgcn_mfma_f32_16x16x32_bf16(a, bv[jl][0], acc[kl][0], 0, 0, 0);
        acc[kl][1] = __builtin_amdgcn_mfma_f32_16x16x32_bf16(a, bv[jl][1], acc[kl][1], 0, 0, 0);
      }
    }
  }
}

__global__ __launch_bounds__(256, 2) void gemm_kernel(const ushort_t* __restrict__ At,
                                                      const ushort_t* __restrict__ Wt,
                                                      float* __restrict__ P) {
  __shared__ __align__(16) ushort_t smem[24576];   // 48 KB: Xs 16KB | Ws 32KB

  const int ut = blockIdx.x;       // 0..15
  const int bt = blockIdx.y;       // 0..7
  const int sp = blockIdx.z;       // 0..3
  const int u0 = ut * 32, b0 = bt * 16, n0 = sp * 128;

  const int wv = threadIdx.x >> 6;
  const int lane = threadIdx.x & 63;

  // staging source offsets (elements), swizzle baked in
  int offX[4], offW[8];
#pragma unroll
  for (int it = 0; it < 4; it++) {
    int slot = it * 256 + wv * 64 + lane;          // 0..1023
    int r = slot >> 2, p = slot & 3;
    int q = p ^ (r & 3) ^ ((r >> 2) & 3);
    offX[it] = ((r >> 4) * 128 + (r & 15)) * 512 + q * 8;   // j=r>>4, bl=r&15
  }
#pragma unroll
  for (int it = 0; it < 8; it++) {
    int slot = it * 256 + wv * 64 + lane;          // 0..2047
    int r = slot >> 2, p = slot & 3;
    int q = p ^ (r & 3) ^ ((r >> 2) & 3);
    offW[it] = ((r >> 5) * 512 + (r & 31)) * 512 + q * 8;   // j=r>>5, ul=r&31
  }
  const ushort_t* Ax = At + (size_t)b0 * 512 + n0;
  const ushort_t* Wx = Wt + (size_t)u0 * 512 + n0;

  const int la = lane & 15, q = lane >> 4;
  const int lbx = la * 64 + (q ^ (la & 3) ^ ((la >> 2) & 3)) * 16;

  f32x4 acc[4][2];
#pragma unroll
  for (int a = 0; a < 4; a++)
#pragma unroll
    for (int g = 0; g < 2; g++) acc[a][g] = (f32x4){0.f, 0.f, 0.f, 0.f};

  const char* sm = (const char*)smem;

#pragma unroll 1
  for (int kt = 0; kt < 4; kt++) {
#pragma unroll
    for (int it = 0; it < 4; it++)
      __builtin_amdgcn_global_load_lds(
          (const __attribute__((address_space(1))) unsigned int*)(Ax + offX[it] + kt * 32),
          (__attribute__((address_space(3))) unsigned int*)(&smem[(it * 256 + wv * 64) * 8]),
          16, 0, 0);
#pragma unroll
    for (int it = 0; it < 8; it++)
      __builtin_amdgcn_global_load_lds(
          (const __attribute__((address_space(1))) unsigned int*)(Wx + offW[it] + kt * 32),
          (__attribute__((address_space(3))) unsigned int*)(&smem[8192 + (it * 256 + wv * 64) * 8]),
          16, 0, 0);
    __syncthreads();
    switch (wv) {
      case 0: compute_chunk<0>(sm, lbx, acc); break;
      case 1: compute_chunk<1>(sm, lbx, acc); break;
      case 2: compute_chunk<2>(sm, lbx, acc); break;
      default: compute_chunk<3>(sm, lbx, acc); break;
    }
    __syncthreads();
  }

  // epilogue: P[((sp*16+k)*128 + b0+row)*512 + u0 + col]
  float* Pb = P + (size_t)sp * 16 * 128 * 512;
#pragma unroll
  for (int kl = 0; kl < 4; kl++) {
    int k = wv * 4 + kl;
#pragma unroll
    for (int g = 0; g < 2; g++)
#pragma unroll
      for (int r2 = 0; r2 < 4; r2++) {
        int row = b0 + q * 4 + r2;           // C/D: row = quad*4 + reg (m89)
        int col = u0 + g * 16 + la;          //      col = lane&15
        Pb[((size_t)(k * 128 + row)) * 512 + col] = acc[kl][g][r2];
      }
  }
}

// ---------------------------------------------------------------------------
// reduce: out[b,u,k] = bias[u,k] + sum_s P[s][k][b][u]
// ---------------------------------------------------------------------------
__global__ __launch_bounds__(256) void reduce_kernel(const float* __restrict__ P,
                                                     const float* __restrict__ bias,
                                                     float* __restrict__ out) {
  int t = blockIdx.x * 256 + threadIdx.x;   // 65536 threads: (b,u)
  int u = t & 511;
  int b = t >> 9;
  float acc[16];
#pragma unroll
  for (int k = 0; k < 16; k++) acc[k] = bias[u * 16 + k];
  for (int s = 0; s < NSPLIT; s++) {
#pragma unroll
    for (int k = 0; k < 16; k++)
      acc[k] += P[((size_t)(s * 16 + k) * 128 + b) * 512 + u];
  }
  float* op = out + ((size_t)(b * 512 + u)) * 16;
#pragma unroll
  for (int qq = 0; qq < 4; qq++)
    ((float4*)op)[qq] = make_float4(acc[qq * 4 + 0], acc[qq * 4 + 1],
                                    acc[qq * 4 + 2], acc[qq * 4 + 3]);
}

// ---------------------------------------------------------------------------
// fallback (ws too small): exact fp32, slow but correct
// ---------------------------------------------------------------------------
__global__ __launch_bounds__(256) void naive_kernel(const float* __restrict__ x,
                                                    const float* __restrict__ w,
                                                    const float* __restrict__ bias,
                                                    float* __restrict__ out) {
  int t = blockIdx.x * 256 + threadIdx.x;
  if (t >= 128 * 512 * 16) return;
  int k = t & 15;
  int u = (t >> 4) & 511;
  int b = t >> 13;
  float sgn[16];
#pragma unroll
  for (int i = 0; i < 16; i++) sgn[i] = (float)ga_sign_i(i, i ^ k);
  float acc = bias[u * 16 + k];
  for (int n = 0; n < 512; n++) {
    const float* xp = x + ((size_t)(b * 512 + n)) * 16;
    const float* wp = w + ((size_t)(u * 512 + n)) * 16;
#pragma unroll
    for (int i = 0; i < 16; i++)
      acc += xp[i] * sgn[i] * wp[i ^ k];
  }
  out[t] = acc;
}

extern "C" void kernel_launch(void* const* d_in, const int* in_sizes, int n_in,
                              void* d_out, int out_size, void* d_ws, size_t ws_size,
                              hipStream_t stream) {
  const float* x    = (const float*)d_in[0];
  const float* w    = (const float*)d_in[1];
  const float* bias = (const float*)d_in[2];
  float* out = (float*)d_out;

  if (ws_size >= WS_NEEDED && d_ws != nullptr) {
    ushort_t* At = (ushort_t*)d_ws;
    ushort_t* Wt = At + AT_ELEMS;
    float* P = (float*)((char*)d_ws + P_OFF_BYTES);

    prep_kernel<<<PREP_TOT / 256, 256, 0, stream>>>(x, w, At, Wt);
    gemm_kernel<<<dim3(16, 8, NSPLIT), 256, 0, stream>>>(At, Wt, P);
    reduce_kernel<<<256, 256, 0, stream>>>(P, bias, out);
  } else {
    naive_kernel<<<(128 * 512 * 16) / 256, 256, 0, stream>>>(x, w, bias, out);
  }
}

// Round 4
// 104.374 us; speedup vs baseline: 1.0300x; 1.0300x over previous
//
#include <hip/hip_runtime.h>
#include <stdint.h>

typedef unsigned short ushort_t;
typedef __attribute__((ext_vector_type(8))) short short8v;   // 8 x bf16
typedef __attribute__((ext_vector_type(4))) float f32x4;     // MFMA acc

#define NSPLIT 2

// ws: At bf16 [16][128][512] (2 MiB) | Wt bf16 [16][512][512] (8 MiB) | P f32 [2][16][128][512] (8 MiB)
#define AT_ELEMS (16u * 128u * 512u)
#define WT_ELEMS (16u * 512u * 512u)
#define P_OFF_BYTES ((size_t)(AT_ELEMS + WT_ELEMS) * 2u)
#define P_ELEMS ((size_t)NSPLIT * 16 * 128 * 512)
#define WS_NEEDED (P_OFF_BYTES + P_ELEMS * 4u)

__host__ __device__ constexpr int ga_sign_i(int a, int b) {
  int t = a >> 1, sw = 0;
  while (t) {
    int x = t & b;
    while (x) { sw += x & 1; x >>= 1; }
    t >>= 1;
  }
  return (sw & 1) ? -1 : 1;
}

struct SignTab { int s[16][16]; };
constexpr SignTab make_tab() {
  SignTab t{};
  for (int i = 0; i < 16; i++)
    for (int j = 0; j < 16; j++) t.s[i][j] = ga_sign_i(i, j);
  return t;
}
constexpr SignTab STAB = make_tab();

__device__ __forceinline__ ushort_t f2bf(float f) {
  unsigned u = __float_as_uint(f);
  u = (u + 0x7FFFu + ((u >> 16) & 1u)) >> 16;   // RNE
  return (ushort_t)u;
}

__device__ __forceinline__ short8v neg_bf16x8(short8v v) {
  const short m = (short)0x8000;
  return v ^ (short8v){m, m, m, m, m, m, m, m};
}

// ---------------------------------------------------------------------------
// prep: At[j][b][n] = bf16(x[b,n,j]);  Wt[j][u][n] = bf16(w[u,n,j])
// thread <-> (row, n-octet). Reads: 8 x 64B contiguous per thread (all 16 j),
// L1 recycles the wave's 32KB span. Stores: 16 coalesced uint4 (1 KB/instr).
// ---------------------------------------------------------------------------
#define PREP_XT (128 * 64)                 // 8192  (row,n8) for x
#define PREP_TOT (PREP_XT + 512 * 64)      // 40960 -> 160 blocks

__global__ __launch_bounds__(256) void prep_kernel(const float* __restrict__ x,
                                                   const float* __restrict__ w,
                                                   ushort_t* __restrict__ At,
                                                   ushort_t* __restrict__ Wt) {
  int tid = blockIdx.x * 256 + threadIdx.x;
  const float* src;
  ushort_t* dst;
  int row, n8, rows;
  if (tid < PREP_XT) {
    n8 = tid & 63; row = tid >> 6; rows = 128;
    src = x; dst = At;
  } else {
    int t = tid - PREP_XT;
    n8 = t & 63; row = t >> 6; rows = 512;
    src = w; dst = Wt;
  }
  ushort_t o[16][8];
#pragma unroll
  for (int r = 0; r < 8; r++) {
    const float4* p = (const float4*)(src + ((size_t)(row * 512 + n8 * 8 + r)) * 16);
    float4 v0 = p[0], v1 = p[1], v2 = p[2], v3 = p[3];
    o[0][r]  = f2bf(v0.x); o[1][r]  = f2bf(v0.y); o[2][r]  = f2bf(v0.z); o[3][r]  = f2bf(v0.w);
    o[4][r]  = f2bf(v1.x); o[5][r]  = f2bf(v1.y); o[6][r]  = f2bf(v1.z); o[7][r]  = f2bf(v1.w);
    o[8][r]  = f2bf(v2.x); o[9][r]  = f2bf(v2.y); o[10][r] = f2bf(v2.z); o[11][r] = f2bf(v2.w);
    o[12][r] = f2bf(v3.x); o[13][r] = f2bf(v3.y); o[14][r] = f2bf(v3.z); o[15][r] = f2bf(v3.w);
  }
#pragma unroll
  for (int j = 0; j < 16; j++)
    *(uint4*)(dst + ((size_t)(j * rows + row)) * 512 + n8 * 8) = *(const uint4*)o[j];
}

// ---------------------------------------------------------------------------
// gemm: block = 16b x 16u x all 16k, nsplit=2 (n-range 256 = 8 chunks of 32).
// LDS 32 KB: Xs[16j][16b][32n] | Ws[16j][16u][32n]; 64B rows, 16B chunks
// XOR-swizzled: content chunk q at position q ^ (r&3) ^ ((r>>2)&3).
// Wave W: k = 4W + kl. i = j^k = 4(jh^W) + (jl^kl); sign compile-time.
// ---------------------------------------------------------------------------
template <int W>
__device__ __forceinline__ void compute_chunk(const char* sm, int lbx,
                                              f32x4 (&acc)[4]) {
#pragma unroll
  for (int jh = 0; jh < 4; jh++) {
    const int ig = jh ^ W;
    short8v av[4], avn[4], bv[4];
#pragma unroll
    for (int il = 0; il < 4; il++) {
      av[il] = *(const short8v*)(sm + (ig * 4 + il) * 1024 + lbx);
      avn[il] = neg_bf16x8(av[il]);
    }
#pragma unroll
    for (int jl = 0; jl < 4; jl++)
      bv[jl] = *(const short8v*)(sm + 16384 + (jh * 4 + jl) * 1024 + lbx);
#pragma unroll
    for (int kl = 0; kl < 4; kl++) {
#pragma unroll
      for (int jl = 0; jl < 4; jl++) {
        const int il = jl ^ kl;
        const int i = ig * 4 + il;          // compile-time after unroll
        const int j = jh * 4 + jl;
        const short8v a = (STAB.s[i][j] < 0) ? avn[il] : av[il];
        acc[kl] = __builtin_amdgcn_mfma_f32_16x16x32_bf16(a, bv[jl], acc[kl], 0, 0, 0);
      }
    }
  }
}

__global__ __launch_bounds__(256, 2) void gemm_kernel(const ushort_t* __restrict__ At,
                                                      const ushort_t* __restrict__ Wt,
                                                      float* __restrict__ P) {
  __shared__ __align__(16) ushort_t smem[16384];   // 32 KB: Xs 16KB | Ws 16KB

  const int ut = blockIdx.x;       // 0..31
  const int bt = blockIdx.y;       // 0..7
  const int sp = blockIdx.z;       // 0..1
  const int u0 = ut * 16, b0 = bt * 16, n0 = sp * 256;

  const int wv = threadIdx.x >> 6;
  const int lane = threadIdx.x & 63;

  // staging source offsets (elements), swizzle baked in
  int offX[4], offW[4];
#pragma unroll
  for (int it = 0; it < 4; it++) {
    int slot = it * 256 + wv * 64 + lane;          // 0..1023
    int r = slot >> 2, p = slot & 3;
    int q = p ^ (r & 3) ^ ((r >> 2) & 3);
    int j = r >> 4, rw = r & 15;
    offX[it] = (j * 128 + rw) * 512 + q * 8;
    offW[it] = (j * 512 + rw) * 512 + q * 8;
  }
  const ushort_t* Ax = At + (size_t)b0 * 512 + n0;
  const ushort_t* Wx = Wt + (size_t)u0 * 512 + n0;

  const int la = lane & 15, q = lane >> 4;
  const int lbx = la * 64 + (q ^ (la & 3) ^ ((la >> 2) & 3)) * 16;

  f32x4 acc[4];
#pragma unroll
  for (int a = 0; a < 4; a++) acc[a] = (f32x4){0.f, 0.f, 0.f, 0.f};

  const char* sm = (const char*)smem;

#pragma unroll 1
  for (int kt = 0; kt < 8; kt++) {
#pragma unroll
    for (int it = 0; it < 4; it++)
      __builtin_amdgcn_global_load_lds(
          (const __attribute__((address_space(1))) unsigned int*)(Ax + offX[it] + kt * 32),
          (__attribute__((address_space(3))) unsigned int*)(&smem[(it * 256 + wv * 64) * 8]),
          16, 0, 0);
#pragma unroll
    for (int it = 0; it < 4; it++)
      __builtin_amdgcn_global_load_lds(
          (const __attribute__((address_space(1))) unsigned int*)(Wx + offW[it] + kt * 32),
          (__attribute__((address_space(3))) unsigned int*)(&smem[8192 + (it * 256 + wv * 64) * 8]),
          16, 0, 0);
    __syncthreads();
    switch (wv) {
      case 0: compute_chunk<0>(sm, lbx, acc); break;
      case 1: compute_chunk<1>(sm, lbx, acc); break;
      case 2: compute_chunk<2>(sm, lbx, acc); break;
      default: compute_chunk<3>(sm, lbx, acc); break;
    }
    __syncthreads();
  }

  // epilogue: P[((sp*16+k)*128 + b0+row)*512 + u0 + col]
  float* Pb = P + (size_t)sp * 16 * 128 * 512;
#pragma unroll
  for (int kl = 0; kl < 4; kl++) {
    int k = wv * 4 + kl;
#pragma unroll
    for (int r2 = 0; r2 < 4; r2++) {
      int row = b0 + q * 4 + r2;           // C/D: row = quad*4 + reg (m89)
      int col = u0 + la;                   //      col = lane&15
      Pb[((size_t)(k * 128 + row)) * 512 + col] = acc[kl][r2];
    }
  }
}

// ---------------------------------------------------------------------------
// reduce: out[b,u,k] = bias[u,k] + sum_s P[s][k][b][u]
// ---------------------------------------------------------------------------
__global__ __launch_bounds__(256) void reduce_kernel(const float* __restrict__ P,
                                                     const float* __restrict__ bias,
                                                     float* __restrict__ out) {
  int t = blockIdx.x * 256 + threadIdx.x;   // 65536 threads: (b,u)
  int u = t & 511;
  int b = t >> 9;
  float acc[16];
#pragma unroll
  for (int k = 0; k < 16; k++) acc[k] = bias[u * 16 + k];
  for (int s = 0; s < NSPLIT; s++) {
#pragma unroll
    for (int k = 0; k < 16; k++)
      acc[k] += P[((size_t)(s * 16 + k) * 128 + b) * 512 + u];
  }
  float* op = out + ((size_t)(b * 512 + u)) * 16;
#pragma unroll
  for (int qq = 0; qq < 4; qq++)
    ((float4*)op)[qq] = make_float4(acc[qq * 4 + 0], acc[qq * 4 + 1],
                                    acc[qq * 4 + 2], acc[qq * 4 + 3]);
}

// ---------------------------------------------------------------------------
// fallback (ws too small): exact fp32, slow but correct
// ---------------------------------------------------------------------------
__global__ __launch_bounds__(256) void naive_kernel(const float* __restrict__ x,
                                                    const float* __restrict__ w,
                                                    const float* __restrict__ bias,
                                                    float* __restrict__ out) {
  int t = blockIdx.x * 256 + threadIdx.x;
  if (t >= 128 * 512 * 16) return;
  int k = t & 15;
  int u = (t >> 4) & 511;
  int b = t >> 13;
  float sgn[16];
#pragma unroll
  for (int i = 0; i < 16; i++) sgn[i] = (float)ga_sign_i(i, i ^ k);
  float acc = bias[u * 16 + k];
  for (int n = 0; n < 512; n++) {
    const float* xp = x + ((size_t)(b * 512 + n)) * 16;
    const float* wp = w + ((size_t)(u * 512 + n)) * 16;
#pragma unroll
    for (int i = 0; i < 16; i++)
      acc += xp[i] * sgn[i] * wp[i ^ k];
  }
  out[t] = acc;
}

extern "C" void kernel_launch(void* const* d_in, const int* in_sizes, int n_in,
                              void* d_out, int out_size, void* d_ws, size_t ws_size,
                              hipStream_t stream) {
  const float* x    = (const float*)d_in[0];
  const float* w    = (const float*)d_in[1];
  const float* bias = (const float*)d_in[2];
  float* out = (float*)d_out;

  if (ws_size >= WS_NEEDED && d_ws != nullptr) {
    ushort_t* At = (ushort_t*)d_ws;
    ushort_t* Wt = At + AT_ELEMS;
    float* P = (float*)((char*)d_ws + P_OFF_BYTES);

    prep_kernel<<<PREP_TOT / 256, 256, 0, stream>>>(x, w, At, Wt);
    gemm_kernel<<<dim3(32, 8, NSPLIT), 256, 0, stream>>>(At, Wt, P);
    reduce_kernel<<<256, 256, 0, stream>>>(P, bias, out);
  } else {
    naive_kernel<<<(128 * 512 * 16) / 256, 256, 0, stream>>>(x, w, bias, out);
  }
}

// Round 5
// 94.865 us; speedup vs baseline: 1.1333x; 1.1002x over previous
//
#include <hip/hip_runtime.h>
#include <stdint.h>

typedef unsigned short ushort_t;
typedef __attribute__((ext_vector_type(8))) short short8v;   // 8 x bf16
typedef __attribute__((ext_vector_type(4))) float f32x4;     // MFMA acc

// ws: At bf16 [16][128][512] (2 MiB) | Wt bf16 [16][512][512] (8 MiB)
#define AT_ELEMS (16u * 128u * 512u)
#define WT_ELEMS (16u * 512u * 512u)
#define WS_NEEDED ((size_t)(AT_ELEMS + WT_ELEMS) * 2u)

__host__ __device__ constexpr int ga_sign_i(int a, int b) {
  int t = a >> 1, sw = 0;
  while (t) {
    int x = t & b;
    while (x) { sw += x & 1; x >>= 1; }
    t >>= 1;
  }
  return (sw & 1) ? -1 : 1;
}

struct SignTab { int s[16][16]; };
constexpr SignTab make_tab() {
  SignTab t{};
  for (int i = 0; i < 16; i++)
    for (int j = 0; j < 16; j++) t.s[i][j] = ga_sign_i(i, j);
  return t;
}
constexpr SignTab STAB = make_tab();

__device__ __forceinline__ ushort_t f2bf(float f) {
  unsigned u = __float_as_uint(f);
  u = (u + 0x7FFFu + ((u >> 16) & 1u)) >> 16;   // RNE
  return (ushort_t)u;
}

__device__ __forceinline__ short8v neg_bf16x8(short8v v) {
  const short m = (short)0x8000;
  return v ^ (short8v){m, m, m, m, m, m, m, m};
}

// ---------------------------------------------------------------------------
// prep (R2-proven pattern): At[j][b][n] = bf16(x[b,n,j]); Wt[j][u][n] = bf16(w[u,n,j])
// Reads: 64 B contiguous per thread, aggregate-coalesced across the wave.
// Stores: 16 scalar bf16, lanes = consecutive n -> 128 B/wave per instr.
// ---------------------------------------------------------------------------
#define PREP_XT (128 * 512)
#define PREP_TOT (PREP_XT + 512 * 512)   // 327,680 -> 1280 blocks

__global__ __launch_bounds__(256) void prep_kernel(const float* __restrict__ x,
                                                   const float* __restrict__ w,
                                                   ushort_t* __restrict__ At,
                                                   ushort_t* __restrict__ Wt) {
  int tid = blockIdx.x * 256 + threadIdx.x;
  if (tid < PREP_XT) {
    int n = tid & 511, b = tid >> 9;
    const float4* xp = (const float4*)(x + (size_t)tid * 16);
    float v[16];
#pragma unroll
    for (int qq = 0; qq < 4; qq++) {
      float4 t = xp[qq];
      v[qq * 4 + 0] = t.x; v[qq * 4 + 1] = t.y; v[qq * 4 + 2] = t.z; v[qq * 4 + 3] = t.w;
    }
#pragma unroll
    for (int j = 0; j < 16; j++)
      At[((size_t)(j * 128 + b)) * 512 + n] = f2bf(v[j]);
  } else {
    int t = tid - PREP_XT;
    int n = t & 511, u = t >> 9;
    const float4* wp = (const float4*)(w + (size_t)t * 16);
    float v[16];
#pragma unroll
    for (int qq = 0; qq < 4; qq++) {
      float4 tt = wp[qq];
      v[qq * 4 + 0] = tt.x; v[qq * 4 + 1] = tt.y; v[qq * 4 + 2] = tt.z; v[qq * 4 + 3] = tt.w;
    }
#pragma unroll
    for (int j = 0; j < 16; j++)
      Wt[((size_t)(j * 512 + u)) * 512 + n] = f2bf(v[j]);
  }
}

// ---------------------------------------------------------------------------
// gemm: ONE kernel, no n-split, no P, bias fused.
// Block = 16b x 16u x ALL 16 k; 4 waves split n into quarters; each wave holds
// all 16 i-frags + reads 16 j-frags per chunk -> 256 MFMA from 32 ds_reads
// (k-reuse: 4x less LDS traffic than k-split-across-waves).
// LDS 128 KB: Xs[16j][16b][128n] (64 KB) | Ws[16j][16u][128n] (64 KB);
// 256 B rows of 16x16B positions, stored at ps = p ^ (row&7) (DMA-compatible,
// conflict-free b128 frag reads). Grid 8bt x 32ut = 256 blocks (1/CU).
// Epilogue: cross-wave n-reduction via LDS + bias + coalesced float4 out.
// ---------------------------------------------------------------------------
__global__ __launch_bounds__(256, 1) void gemm_kernel(const ushort_t* __restrict__ At,
                                                      const ushort_t* __restrict__ Wt,
                                                      const float* __restrict__ bias,
                                                      float* __restrict__ out) {
  __shared__ __align__(16) ushort_t smem[65536];   // 128 KB

  const int ut = blockIdx.x;       // 0..31
  const int bt = blockIdx.y;       // 0..7
  const int u0 = ut * 16, b0 = bt * 16;

  const int tid = threadIdx.x;
  const int wv = tid >> 6, lane = tid & 63;
  const int la = lane & 15, q = lane >> 4;

  // --- staging (DMA) addressing: thread -> (row = tid>>4, ps = tid&15) ---
  const int srow = tid >> 4;
  const int sps = tid & 15;
  const int sp = sps ^ (srow & 7);          // content position in the 256B row
  const int sc = sp >> 2, sq = sp & 3;      // n = c*32 + q*8 (+ kt*128)

  const ushort_t* AxB = At + (size_t)(b0 + srow) * 512 + sc * 32 + sq * 8;
  const ushort_t* WxB = Wt + (size_t)(u0 + srow) * 512 + sc * 32 + sq * 8;

  // --- frag read addressing ---
  const int pr = wv * 4 + q;                          // this wave's n-quarter, this quad's 16B pos
  const int lbx = la * 256 + ((pr ^ (la & 7)) * 16);  // byte offset within a j-block (4096 B)

  f32x4 acc[16];
#pragma unroll
  for (int k = 0; k < 16; k++) acc[k] = (f32x4){0.f, 0.f, 0.f, 0.f};

  const char* sm = (const char*)smem;

#pragma unroll 1
  for (int kt = 0; kt < 4; kt++) {
#pragma unroll
    for (int i = 0; i < 16; i++)
      __builtin_amdgcn_global_load_lds(
          (const __attribute__((address_space(1))) unsigned int*)(AxB + (size_t)i * 65536 + kt * 128),
          (__attribute__((address_space(3))) unsigned int*)(&smem[(i * 256 + wv * 64) * 8]),
          16, 0, 0);
#pragma unroll
    for (int i = 0; i < 16; i++)
      __builtin_amdgcn_global_load_lds(
          (const __attribute__((address_space(1))) unsigned int*)(WxB + (size_t)i * 262144 + kt * 128),
          (__attribute__((address_space(3))) unsigned int*)(&smem[32768 + (i * 256 + wv * 64) * 8]),
          16, 0, 0);
    __syncthreads();

    short8v av[16], nav[16];
#pragma unroll
    for (int i = 0; i < 16; i++) {
      av[i] = *(const short8v*)(sm + i * 4096 + lbx);
      nav[i] = neg_bf16x8(av[i]);
    }
#pragma unroll
    for (int j = 0; j < 16; j++) {
      const short8v bvj = *(const short8v*)(sm + 65536 + j * 4096 + lbx);
#pragma unroll
      for (int k = 0; k < 16; k++) {
        const int i = j ^ k;                 // compile-time after unroll
        acc[k] = __builtin_amdgcn_mfma_f32_16x16x32_bf16(
            (STAB.s[i][j] < 0) ? nav[i] : av[i], bvj, acc[k], 0, 0, 0);
      }
    }
    __syncthreads();
  }

  // --- epilogue: cross-wave reduction + bias + out ---
  float* red = (float*)smem;   // reuse first 64 KB: [wv][row16][col16][k16] f32
#pragma unroll
  for (int g = 0; g < 4; g++) {
#pragma unroll
    for (int r2 = 0; r2 < 4; r2++) {
      float4 v = make_float4(acc[g * 4 + 0][r2], acc[g * 4 + 1][r2],
                             acc[g * 4 + 2][r2], acc[g * 4 + 3][r2]);
      int row = q * 4 + r2;                  // C/D: row = quad*4 + reg (m89)
      *(float4*)&red[(((wv * 16 + row) * 16 + la) << 4) + g * 4] = v;
    }
  }
  __syncthreads();

  const int row = tid >> 4, col = tid & 15;
  float4 o[4];
#pragma unroll
  for (int g = 0; g < 4; g++)
    o[g] = *(const float4*)&bias[(u0 + col) * 16 + g * 4];
#pragma unroll
  for (int w2 = 0; w2 < 4; w2++) {
#pragma unroll
    for (int g = 0; g < 4; g++) {
      float4 v = *(const float4*)&red[(((w2 * 16 + row) * 16 + col) << 4) + g * 4];
      o[g].x += v.x; o[g].y += v.y; o[g].z += v.z; o[g].w += v.w;
    }
  }
#pragma unroll
  for (int g = 0; g < 4; g++)
    *(float4*)&out[((size_t)(b0 + row) * 512 + (u0 + col)) * 16 + g * 4] = o[g];
}

// ---------------------------------------------------------------------------
// fallback (ws too small): exact fp32, slow but correct
// ---------------------------------------------------------------------------
__global__ __launch_bounds__(256) void naive_kernel(const float* __restrict__ x,
                                                    const float* __restrict__ w,
                                                    const float* __restrict__ bias,
                                                    float* __restrict__ out) {
  int t = blockIdx.x * 256 + threadIdx.x;
  if (t >= 128 * 512 * 16) return;
  int k = t & 15;
  int u = (t >> 4) & 511;
  int b = t >> 13;
  float sgn[16];
#pragma unroll
  for (int i = 0; i < 16; i++) sgn[i] = (float)ga_sign_i(i, i ^ k);
  float acc = bias[u * 16 + k];
  for (int n = 0; n < 512; n++) {
    const float* xp = x + ((size_t)(b * 512 + n)) * 16;
    const float* wp = w + ((size_t)(u * 512 + n)) * 16;
#pragma unroll
    for (int i = 0; i < 16; i++)
      acc += xp[i] * sgn[i] * wp[i ^ k];
  }
  out[t] = acc;
}

extern "C" void kernel_launch(void* const* d_in, const int* in_sizes, int n_in,
                              void* d_out, int out_size, void* d_ws, size_t ws_size,
                              hipStream_t stream) {
  const float* x    = (const float*)d_in[0];
  const float* w    = (const float*)d_in[1];
  const float* bias = (const float*)d_in[2];
  float* out = (float*)d_out;

  if (ws_size >= WS_NEEDED && d_ws != nullptr) {
    ushort_t* At = (ushort_t*)d_ws;
    ushort_t* Wt = At + AT_ELEMS;

    prep_kernel<<<PREP_TOT / 256, 256, 0, stream>>>(x, w, At, Wt);
    gemm_kernel<<<dim3(32, 8), 256, 0, stream>>>(At, Wt, bias, out);
  } else {
    naive_kernel<<<(128 * 512 * 16) / 256, 256, 0, stream>>>(x, w, bias, out);
  }
}